// Round 5
// baseline (61.919 us; speedup 1.0000x reference)
//
#include <hip/hip_runtime.h>

#define TPB 256
#define PRED_CH 30
#define GT_CH 25

// IEEE-exact helpers: prevent fma contraction so the IoU chain matches numpy
// float32 bit-for-bit (argmax flips would cost absmax=1.0 on obj_ij).
__device__ __forceinline__ float mul_rn(float a, float b) { return __fmul_rn(a, b); }
__device__ __forceinline__ float add_rn(float a, float b) { return __fadd_rn(a, b); }
__device__ __forceinline__ float sub_rn(float a, float b) { return __fsub_rn(a, b); }

__device__ __forceinline__ void to_xyxy(float x, float y, float w, float h,
                                        float gi, float gj, float o[4]) {
    float cx = mul_rn(64.0f, add_rn(x, gi));
    float cy = mul_rn(64.0f, add_rn(y, gj));
    float W  = mul_rn(w, 448.0f);
    float H  = mul_rn(h, 448.0f);
    float Wh = mul_rn(W, 0.5f);
    float Hh = mul_rn(H, 0.5f);
    o[0] = sub_rn(cx, Wh);
    o[1] = sub_rn(cy, Hh);
    o[2] = add_rn(cx, Wh);
    o[3] = add_rn(cy, Hh);
    if (x == 0.0f && y == 0.0f && w == 0.0f && h == 0.0f) {
        o[0] = o[1] = o[2] = o[3] = 0.0f;
    }
}

__device__ __forceinline__ float iou_box(const float pb[5] /* conf,x,y,w,h */,
                                         const float gb[4], float areag,
                                         float gi, float gj) {
    float p[4];
    to_xyxy(pb[1], pb[2], pb[3], pb[4], gi, gj, p);
    float lx = fmaxf(gb[0], p[0]);
    float ly = fmaxf(gb[1], p[1]);
    float rx = fminf(gb[2], p[2]);
    float ry = fminf(gb[3], p[3]);
    float iw = fmaxf(sub_rn(rx, lx), 0.0f);
    float ih = fmaxf(sub_rn(ry, ly), 0.0f);
    float inter = mul_rn(iw, ih);
    float areap = mul_rn(sub_rn(p[2], p[0]), sub_rn(p[3], p[1]));
    float denom = sub_rn(add_rn(areag, areap), inter);  // left-to-right, as numpy
    return __fdiv_rn(inter, denom);
}

// Pure streaming, NO LDS, NO barriers. Each thread owns TWO cells:
//   pred slice = 60 floats = 240 B -> 16B-aligned -> 15 x float4
//   gt   slice = 50 floats = 200 B ->  8B-aligned -> 25 x float2
// A wave reads contiguous 15.4 KB / 12.8 KB windows (fits L1, every line
// fully consumed); ~21 loads in flight per thread hide HBM latency via ILP.
// This removes round-4's convoy: issue-loads -> vmcnt(0) drain -> compute
// left the memory system idle in bursts, pinning us at ~2x the BW floor.
__global__ __launch_bounds__(TPB) void yolo_main(const float* __restrict__ pred,
                                                 const float* __restrict__ gt,
                                                 float* __restrict__ out,
                                                 float* __restrict__ partials,
                                                 int npairs) {
    __shared__ float wsum[TPB / 64];
    const int t = blockIdx.x * TPB + threadIdx.x;

    float lsum = 0.0f;
    if (t < npairs) {
        float P[2 * PRED_CH];
        float G[2 * GT_CH];
        {
            const float4* pp = reinterpret_cast<const float4*>(pred + (size_t)t * (2 * PRED_CH));
#pragma unroll
            for (int k = 0; k < 15; ++k) {        // constant indices after unroll -> registers
                float4 v = pp[k];
                P[4 * k]     = v.x;
                P[4 * k + 1] = v.y;
                P[4 * k + 2] = v.z;
                P[4 * k + 3] = v.w;
            }
            const float2* gg = reinterpret_cast<const float2*>(gt + (size_t)t * (2 * GT_CH));
#pragma unroll
            for (int k = 0; k < 25; ++k) {
                float2 v = gg[k];
                G[2 * k]     = v.x;
                G[2 * k + 1] = v.y;
            }
        }

        float ob[4];
#pragma unroll
        for (int c = 0; c < 2; ++c) {
            const int cell = 2 * t + c;
            const int po = c * PRED_CH, go = c * GT_CH;

            const float gm = (G[go + 20] == 1.0f) ? 1.0f : 0.0f;

            float cl = 0.0f;
#pragma unroll
            for (int k = 0; k < 20; ++k) {
                float d = P[po + k] - G[go + k];
                cl = fmaf(d, d, cl);
            }
            lsum += cl * gm;

            // cell = (b*7 + i)*7 + j ; cx uses i (axis1), cy uses j (axis2)
            const int rem = cell % 49;
            const int ii  = rem / 7;
            const float gi = (float)ii;
            const float gj = (float)(rem - ii * 7);

            float gb[4];
            to_xyxy(G[go + 21], G[go + 22], G[go + 23], G[go + 24], gi, gj, gb);
            const float areag = mul_rn(sub_rn(gb[2], gb[0]), sub_rn(gb[3], gb[1]));

            float pb0[5] = {P[po + 20], P[po + 21], P[po + 22], P[po + 23], P[po + 24]};
            float pb1[5] = {P[po + 25], P[po + 26], P[po + 27], P[po + 28], P[po + 29]};
            const float iou0 = iou_box(pb0, gb, areag, gi, gj);
            const float iou1 = iou_box(pb1, gb, areag, gi, gj);

            const int sel = (iou1 > iou0) ? 1 : 0;   // numpy argmax: first max wins

            ob[2 * c]     = (sel == 0) ? gm : 0.0f;
            ob[2 * c + 1] = (sel == 1) ? gm : 0.0f;
        }

        // 4 consecutive dwords (out+1 base is only 4B-aligned -> dword stores)
        float* op = out + 1 + 4 * (size_t)t;
        op[0] = ob[0];
        op[1] = ob[1];
        op[2] = ob[2];
        op[3] = ob[3];
    }

    // ---- block reduce class loss; ONE plain store per block (no atomics) ----
#pragma unroll
    for (int off = 32; off > 0; off >>= 1) lsum += __shfl_down(lsum, off);
    const int wid = threadIdx.x >> 6, lane = threadIdx.x & 63;
    if (lane == 0) wsum[wid] = lsum;
    __syncthreads();
    if (threadIdx.x == 0) {
        partials[blockIdx.x] = wsum[0] + wsum[1] + wsum[2] + wsum[3];
    }
}

// Single-block fixed-order reduction of per-block partials -> out[0].
__global__ __launch_bounds__(1024) void yolo_reduce(const float* __restrict__ partials,
                                                    float* __restrict__ out,
                                                    int nblocks, float inv_b) {
    __shared__ float w[16];
    float s = 0.0f;
    for (int i = threadIdx.x; i < nblocks; i += 1024) s += partials[i];
#pragma unroll
    for (int off = 32; off > 0; off >>= 1) s += __shfl_down(s, off);
    if ((threadIdx.x & 63) == 0) w[threadIdx.x >> 6] = s;
    __syncthreads();
    if (threadIdx.x == 0) {
        float t = 0.0f;
#pragma unroll
        for (int k = 0; k < 16; ++k) t += w[k];
        out[0] = t * inv_b;
    }
}

extern "C" void kernel_launch(void* const* d_in, const int* in_sizes, int n_in,
                              void* d_out, int out_size, void* d_ws, size_t ws_size,
                              hipStream_t stream) {
    const float* pred = (const float*)d_in[0];
    const float* gt   = (const float*)d_in[1];
    float* out      = (float*)d_out;
    float* partials = (float*)d_ws;

    const int ncells = in_sizes[0] / PRED_CH;      // B*7*7 = 802816 (even)
    const int batch  = ncells / 49;
    const int npairs = ncells / 2;                 // 401408
    const int blocks = (npairs + TPB - 1) / TPB;   // 1568

    yolo_main<<<blocks, TPB, 0, stream>>>(pred, gt, out, partials, npairs);
    yolo_reduce<<<1, 1024, 0, stream>>>(partials, out, blocks, 1.0f / (float)batch);
}

// Round 6
// 35.609 us; speedup vs baseline: 1.7389x; 1.7389x over previous
//
#include <hip/hip_runtime.h>

#define TPB 256
#define CPB 128                      // cells per tile
#define TT  8                        // tiles per block
#define PRED_CH 30
#define GT_CH 25
#define PF4 (CPB * PRED_CH / 4)      // 960 float4 per pred tile
#define GF4 (CPB * GT_CH / 4)        // 800 float4 per gt tile

// IEEE-exact helpers: prevent fma contraction so the IoU chain matches numpy
// float32 bit-for-bit (argmax flips would cost absmax=1.0 on obj_ij).
__device__ __forceinline__ float mul_rn(float a, float b) { return __fmul_rn(a, b); }
__device__ __forceinline__ float add_rn(float a, float b) { return __fadd_rn(a, b); }
__device__ __forceinline__ float sub_rn(float a, float b) { return __fsub_rn(a, b); }

// async global->LDS, 16B per lane. HW semantics (m104): LDS dest is wave-
// uniform base + lane*16 — our per-lane ptr &s[start+lane] is exactly that.
__device__ __forceinline__ void load_lds16(const void* g, void* l) {
    __builtin_amdgcn_global_load_lds(
        (const __attribute__((address_space(1))) void*)g,
        (__attribute__((address_space(3))) void*)l, 16, 0, 0);
}

__device__ __forceinline__ void to_xyxy(float x, float y, float w, float h,
                                        float gi, float gj, float o[4]) {
    float cx = mul_rn(64.0f, add_rn(x, gi));
    float cy = mul_rn(64.0f, add_rn(y, gj));
    float W  = mul_rn(w, 448.0f);
    float H  = mul_rn(h, 448.0f);
    float Wh = mul_rn(W, 0.5f);
    float Hh = mul_rn(H, 0.5f);
    o[0] = sub_rn(cx, Wh);
    o[1] = sub_rn(cy, Hh);
    o[2] = add_rn(cx, Wh);
    o[3] = add_rn(cy, Hh);
    if (x == 0.0f && y == 0.0f && w == 0.0f && h == 0.0f) {
        o[0] = o[1] = o[2] = o[3] = 0.0f;
    }
}

__device__ __forceinline__ float iou_box(const float pb[5] /* conf,x,y,w,h */,
                                         const float gb[4], float areag,
                                         float gi, float gj) {
    float p[4];
    to_xyxy(pb[1], pb[2], pb[3], pb[4], gi, gj, p);
    float lx = fmaxf(gb[0], p[0]);
    float ly = fmaxf(gb[1], p[1]);
    float rx = fminf(gb[2], p[2]);
    float ry = fminf(gb[3], p[3]);
    float iw = fmaxf(sub_rn(rx, lx), 0.0f);
    float ih = fmaxf(sub_rn(ry, ly), 0.0f);
    float inter = mul_rn(iw, ih);
    float areap = mul_rn(sub_rn(p[2], p[0]), sub_rn(p[3], p[1]));
    float denom = sub_rn(add_rn(areag, areap), inter);  // left-to-right, as numpy
    return __fdiv_rn(inter, denom);
}

// T3/T4-lite pipeline: double-buffered LDS tiles, counted vmcnt(8) — the
// memory queue NEVER drains to 0 inside the loop (round-4's convoy did:
// issue -> vmcnt(0) -> compute left HBM idle in bursts at 47% util).
// Every wave issues exactly 8 global_load_lds per tile (wave-uniform clamped
// starts; duplicate windows rewrite identical bytes — benign), so each wave's
// own vmcnt(8) == "my previous tile's loads have landed"; s_barrier then
// publishes all waves' data. Raw s_barrier via asm keeps the compiler from
// inserting the vmcnt(0) drain that __syncthreads() implies.
__global__ __launch_bounds__(TPB) void yolo_main(const float* __restrict__ pred,
                                                 const float* __restrict__ gt,
                                                 float* __restrict__ out,
                                                 float* __restrict__ partials,
                                                 int ncells) {
    __shared__ float4 sp[2][PF4];   // 2 x 15360 B
    __shared__ float4 sg[2][GF4];   // 2 x 12800 B
    __shared__ float wsum[TPB / 64];

    const int tid   = threadIdx.x;
    const int lane  = tid & 63;
    const int wb    = tid & ~63;          // wave base: 0,64,128,192
    const int tile0 = blockIdx.x * TT;

    const float4* p4 = reinterpret_cast<const float4*>(pred);
    const float4* g4 = reinterpret_cast<const float4*>(gt);

    auto stage = [&](int tile, int b) {
        const float4* ps = p4 + (size_t)tile * PF4;
        const float4* gs = g4 + (size_t)tile * GF4;
#pragma unroll
        for (int k = 0; k < 4; ++k) {     // pred: 4 wave-slots, clamp start to 896
            int s = wb + k * TPB; if (s > PF4 - 64) s = PF4 - 64; s += lane;
            load_lds16(ps + s, &sp[b][s]);
        }
#pragma unroll
        for (int k = 0; k < 4; ++k) {     // gt: 4 wave-slots, clamp start to 736
            int s = wb + k * TPB; if (s > GF4 - 64) s = GF4 - 64; s += lane;
            load_lds16(gs + s, &sg[b][s]);
        }
    };

    float lsum = 0.0f;

    stage(tile0, 0);   // prologue

    for (int i = 0; i < TT; ++i) {
        if (i + 1 < TT) {
            stage(tile0 + i + 1, (i + 1) & 1);          // prefetch next tile
            asm volatile("s_waitcnt vmcnt(8)" ::: "memory");  // wait tile i only
        } else {
            asm volatile("s_waitcnt vmcnt(0)" ::: "memory");  // epilogue drain
        }
        asm volatile("s_barrier" ::: "memory");

        if (tid < CPB) {
            const float* P = reinterpret_cast<const float*>(&sp[i & 1][0]) + tid * PRED_CH;
            const float* G = reinterpret_cast<const float*>(&sg[i & 1][0]) + tid * GT_CH;
            const int cell = (tile0 + i) * CPB + tid;

            const float gm = (G[20] == 1.0f) ? 1.0f : 0.0f;

            float cl = 0.0f;
#pragma unroll
            for (int c = 0; c < 20; ++c) {
                float d = P[c] - G[c];
                cl = fmaf(d, d, cl);
            }
            lsum += cl * gm;

            // cell = (b*7 + i)*7 + j ; cx uses i (axis1), cy uses j (axis2)
            const int rem = cell % 49;
            const int ii  = rem / 7;
            const float gi = (float)ii;
            const float gj = (float)(rem - ii * 7);

            float gb[4];
            to_xyxy(G[21], G[22], G[23], G[24], gi, gj, gb);
            const float areag = mul_rn(sub_rn(gb[2], gb[0]), sub_rn(gb[3], gb[1]));

            float pb0[5] = {P[20], P[21], P[22], P[23], P[24]};
            float pb1[5] = {P[25], P[26], P[27], P[28], P[29]};
            const float iou0 = iou_box(pb0, gb, areag, gi, gj);
            const float iou1 = iou_box(pb1, gb, areag, gi, gj);

            const int sel = (iou1 > iou0) ? 1 : 0;   // numpy argmax: first max wins

            out[1 + 2 * (size_t)cell]     = (sel == 0) ? gm : 0.0f;
            out[1 + 2 * (size_t)cell + 1] = (sel == 1) ? gm : 0.0f;
        }
        asm volatile("s_barrier" ::: "memory");   // protect buf before overwrite
    }

    // ---- block reduce class loss across all TT tiles; one plain store ----
#pragma unroll
    for (int off = 32; off > 0; off >>= 1) lsum += __shfl_down(lsum, off);
    if (lane == 0) wsum[tid >> 6] = lsum;
    __syncthreads();
    if (tid == 0) {
        partials[blockIdx.x] = wsum[0] + wsum[1] + wsum[2] + wsum[3];
    }
}

// Single-block fixed-order reduction of per-block partials -> out[0].
__global__ __launch_bounds__(1024) void yolo_reduce(const float* __restrict__ partials,
                                                    float* __restrict__ out,
                                                    int nblocks, float inv_b) {
    __shared__ float w[16];
    float s = 0.0f;
    for (int i = threadIdx.x; i < nblocks; i += 1024) s += partials[i];
#pragma unroll
    for (int off = 32; off > 0; off >>= 1) s += __shfl_down(s, off);
    if ((threadIdx.x & 63) == 0) w[threadIdx.x >> 6] = s;
    __syncthreads();
    if (threadIdx.x == 0) {
        float t = 0.0f;
#pragma unroll
        for (int k = 0; k < 16; ++k) t += w[k];
        out[0] = t * inv_b;
    }
}

extern "C" void kernel_launch(void* const* d_in, const int* in_sizes, int n_in,
                              void* d_out, int out_size, void* d_ws, size_t ws_size,
                              hipStream_t stream) {
    const float* pred = (const float*)d_in[0];
    const float* gt   = (const float*)d_in[1];
    float* out      = (float*)d_out;
    float* partials = (float*)d_ws;

    const int ncells = in_sizes[0] / PRED_CH;   // 802816 = 6272 tiles of 128
    const int batch  = ncells / 49;
    const int ntiles = ncells / CPB;            // 6272 (exact)
    const int blocks = ntiles / TT;             // 784 (exact)

    yolo_main<<<blocks, TPB, 0, stream>>>(pred, gt, out, partials, ncells);
    yolo_reduce<<<1, 1024, 0, stream>>>(partials, out, blocks, 1.0f / (float)batch);
}